// Round 1
// baseline (276.240 us; speedup 1.0000x reference)
//
#include <hip/hip_runtime.h>

// ---------------------------------------------------------------------------
// MoE gated MLP with LoRA, top-2 of 8 experts, T=512, H=2048, I=1024, R=16.
// Sparse dispatch (identical math to reference), fp32 router, bf16 MFMA GEMMs.
// ---------------------------------------------------------------------------

#define T_TOK 512
#define H_DIM 2048
#define E_NUM 8
#define I_DIM 1024

typedef short  s16x8 __attribute__((ext_vector_type(8)));
typedef float  f32x4 __attribute__((ext_vector_type(4)));
typedef unsigned short u16x4 __attribute__((ext_vector_type(4)));

__device__ __forceinline__ unsigned short f2bf(float f) {
  unsigned u = __builtin_bit_cast(unsigned, f);
  u += 0x7fffu + ((u >> 16) & 1u);          // RNE
  return (unsigned short)(u >> 16);
}
__device__ __forceinline__ float bf2f(unsigned short b) {
  unsigned u = ((unsigned)b) << 16;
  return __builtin_bit_cast(float, u);
}

// ---- workspace layout (bytes) ----
#define OFF_WG   0u          // 8*2048 f32            = 65536
#define OFF_CNT  65536u      // 8 int (pad 256)
#define OFF_LIST 65792u      // 8*512 int             = 16384
#define OFF_PEXP 82176u      // 1024 int              = 4096
#define OFF_PW   86272u      // 1024 f32              = 4096
#define OFF_TER1 90368u      // 1024*16 f32           = 65536
#define OFF_TER2 155904u     // 1024*16 f32           = 65536
#define OFF_XBF  221440u     // 512*2048 bf16         = 2097152
#define OFF_H    2318592u    // 1024*1024 bf16        = 2097152
// total: 4415744 bytes

// ---------------------------------------------------------------------------
__global__ void k_gatecomb(const float* __restrict__ gw, const float* __restrict__ gA,
                           const float* __restrict__ gB, float* __restrict__ Wg) {
  int idx = blockIdx.x * 256 + threadIdx.x;   // 16384 total
  int e = idx >> 11, h = idx & 2047;
  float acc = gw[idx];
#pragma unroll
  for (int r = 0; r < 16; ++r)
    acc += 2.0f * gB[e * 16 + r] * gA[r * 2048 + h];
  Wg[idx] = acc;
}

__global__ void k_xcvt(const float* __restrict__ x, unsigned short* __restrict__ xbf) {
  int idx = blockIdx.x * 256 + threadIdx.x;   // 262144 total, 4 elems each
  float4 v = ((const float4*)x)[idx];
  u16x4 o = { f2bf(v.x), f2bf(v.y), f2bf(v.z), f2bf(v.w) };
  ((u16x4*)xbf)[idx] = o;
}

// fp32 router: exact logits so top-k matches reference selection.
__global__ void k_router(const float* __restrict__ x, const float* __restrict__ Wg,
                         int* __restrict__ cnt, int* __restrict__ list,
                         int* __restrict__ pexp, float* __restrict__ pw) {
  int t = blockIdx.x, tid = threadIdx.x;
  __shared__ float xs[2048];
  __shared__ float logits[8];
  for (int i = tid; i < 2048; i += 256) xs[i] = x[(size_t)t * 2048 + i];
  __syncthreads();
  int e = tid >> 5, l = tid & 31;
  float s = 0.f;
  for (int h = l; h < 2048; h += 32) s += xs[h] * Wg[e * 2048 + h];
#pragma unroll
  for (int off = 16; off >= 1; off >>= 1) s += __shfl_down(s, off, 32);
  if (l == 0) logits[e] = s;
  __syncthreads();
  if (tid == 0) {
    float m = logits[0];
#pragma unroll
    for (int i = 1; i < 8; ++i) m = fmaxf(m, logits[i]);
    float ex[8];
#pragma unroll
    for (int i = 0; i < 8; ++i) ex[i] = __expf(logits[i] - m);
    int e1 = 0; float v1 = ex[0];
#pragma unroll
    for (int i = 1; i < 8; ++i) if (ex[i] > v1) { v1 = ex[i]; e1 = i; }
    int e2 = -1; float v2 = -1.f;
#pragma unroll
    for (int i = 0; i < 8; ++i) if (i != e1 && ex[i] > v2) { v2 = ex[i]; e2 = i; }
    float inv = 1.f / (v1 + v2);
    int p1 = 2 * t, p2 = 2 * t + 1;
    pexp[p1] = e1; pw[p1] = v1 * inv;
    pexp[p2] = e2; pw[p2] = v2 * inv;
    int s1 = atomicAdd(&cnt[e1], 1); list[e1 * 512 + s1] = p1;
    int s2 = atomicAdd(&cnt[e2], 1); list[e2 * 512 + s2] = p2;
  }
}

// ter1[p][r] = sum_h x[t][h] * gup_lora_A[e][r][h]
__global__ void k_ter1(const float* __restrict__ x, const float* __restrict__ gupA,
                       const int* __restrict__ pexp, float* __restrict__ ter1) {
  int p = blockIdx.x, tid = threadIdx.x;
  int e = pexp[p], t = p >> 1;
  int r = tid >> 4, l = tid & 15;
  const float* xa = x + (size_t)t * 2048;
  const float* Aa = gupA + ((size_t)e * 16 + r) * 2048;
  float s = 0.f;
  for (int h = l; h < 2048; h += 16) s += xa[h] * Aa[h];
#pragma unroll
  for (int off = 8; off >= 1; off >>= 1) s += __shfl_down(s, off, 16);
  if (l == 0) ter1[p * 16 + r] = s;
}

// ter2[p][r] = sum_i h[p][i] * down_lora_A[e][r][i]
__global__ void k_ter2(const unsigned short* __restrict__ hws, const float* __restrict__ dlA,
                       const int* __restrict__ pexp, float* __restrict__ ter2) {
  int p = blockIdx.x, tid = threadIdx.x;
  int e = pexp[p];
  int r = tid >> 4, l = tid & 15;
  const unsigned short* ha = hws + (size_t)p * 1024;
  const float* Aa = dlA + ((size_t)e * 16 + r) * 1024;
  float s = 0.f;
  for (int i = l; i < 1024; i += 16) s += bf2f(ha[i]) * Aa[i];
#pragma unroll
  for (int off = 8; off >= 1; off >>= 1) s += __shfl_down(s, off, 16);
  if (l == 0) ter2[p * 16 + r] = s;
}

// GEMM1: per expert, [n_e,2048] x [2048, 64g+64u cols] -> h (silu(g')*u'), bf16 out.
// Block: 64 tokens x (64 gate cols + 64 up cols), 4 waves, each wave 64 rows x 16 cols.
__global__ __launch_bounds__(256) void k_gemm1(
    const unsigned short* __restrict__ xbf, const float* __restrict__ gup,
    const float* __restrict__ gupB, const float* __restrict__ ter1,
    const int* __restrict__ cnt, const int* __restrict__ list,
    unsigned short* __restrict__ hws) {
  int ct = blockIdx.x, st = blockIdx.y, e = blockIdx.z;
  int n = cnt[e];
  if (st * 64 >= n) return;
  int tid = threadIdx.x;

  __shared__ int plist_s[64];
  __shared__ float ters[64][16];
  __shared__ unsigned short Asub[64 * 64];       // [row][k] XOR-swizzled (16B blocks)
  __shared__ unsigned short Bsub[2][64 * 64];    // [k][c], col XOR by (k>>3)&3

  if (tid < 64) plist_s[tid] = list[e * 512 + min(st * 64 + tid, n - 1)];
  __syncthreads();
  for (int i = tid; i < 64 * 16; i += 256)
    ters[i >> 4][i & 15] = ter1[plist_s[i >> 4] * 16 + (i & 15)];

  int lane = tid & 63, wv = tid >> 6;
  int lr = lane & 15, lh = lane >> 4;
  int wc = wv * 16;
  int cg0 = ct * 64;

  f32x4 accg[4] = {};
  f32x4 accu[4] = {};

  for (int kt = 0; kt < 32; ++kt) {
    int k0 = kt * 64;
    __syncthreads();
    // stage A (gathered token rows, bf16)
#pragma unroll
    for (int q = 0; q < 2; ++q) {
      int lin = tid + q * 256;
      int row = lin >> 3, k8 = (lin & 7) * 8;
      uint4 v = *(const uint4*)(xbf + (size_t)(plist_s[row] >> 1) * 2048 + k0 + k8);
      *(uint4*)&Asub[row * 64 + (k8 ^ ((row & 7) << 3))] = v;
    }
    // stage B: gates half and ups half, fp32 -> bf16
#pragma unroll
    for (int half = 0; half < 2; ++half) {
      const float* Wp = gup + (size_t)e * 2048 * 2048 + (size_t)k0 * 2048 + (half ? 1024 + cg0 : cg0);
#pragma unroll
      for (int q = 0; q < 4; ++q) {
        int lin = tid + q * 256;
        int k = lin >> 4, c4 = (lin & 15) * 4;
        float4 v = *(const float4*)(Wp + (size_t)k * 2048 + c4);
        u16x4 b = { f2bf(v.x), f2bf(v.y), f2bf(v.z), f2bf(v.w) };
        *(u16x4*)&Bsub[half][k * 64 + (c4 ^ (((k >> 3) & 3) << 4))] = b;
      }
    }
    __syncthreads();
#pragma unroll
    for (int ks = 0; ks < 64; ks += 32) {
      int kb = ks + lh * 8;
      int key = ((kb >> 3) & 3) << 4;
      int colx = (wc + lr) ^ key;
      s16x8 bg, bu;
#pragma unroll
      for (int j = 0; j < 8; ++j) {
        bg[j] = (short)Bsub[0][(kb + j) * 64 + colx];
        bu[j] = (short)Bsub[1][(kb + j) * 64 + colx];
      }
#pragma unroll
      for (int fr = 0; fr < 4; ++fr) {
        int row = fr * 16 + lr;
        s16x8 a = *(const s16x8*)&Asub[row * 64 + (kb ^ ((row & 7) << 3))];
        accg[fr] = __builtin_amdgcn_mfma_f32_16x16x32_bf16(a, bg, accg[fr], 0, 0, 0);
        accu[fr] = __builtin_amdgcn_mfma_f32_16x16x32_bf16(a, bu, accu[fr], 0, 0, 0);
      }
    }
  }
  // epilogue: LoRA delta + silu, write h (bf16)
  int cg = wc + lr;
  const float* g2p = gupB + ((size_t)e * 2048 + cg0 + cg) * 16;
  const float* u2p = gupB + ((size_t)e * 2048 + 1024 + cg0 + cg) * 16;
  float g2[16], u2[16];
#pragma unroll
  for (int r = 0; r < 16; ++r) { g2[r] = g2p[r]; u2[r] = u2p[r]; }
#pragma unroll
  for (int fr = 0; fr < 4; ++fr) {
#pragma unroll
    for (int j = 0; j < 4; ++j) {
      int row = fr * 16 + lh * 4 + j;
      if (st * 64 + row < n) {
        float dg = 0.f, du = 0.f;
#pragma unroll
        for (int r = 0; r < 16; ++r) {
          float tv = ters[row][r];
          dg += tv * g2[r]; du += tv * u2[r];
        }
        float gv = accg[fr][j] + 2.f * dg;
        float uv = accu[fr][j] + 2.f * du;
        float hv = gv / (1.f + __expf(-gv)) * uv;
        hws[(size_t)plist_s[row] * 1024 + cg0 + cg] = f2bf(hv);
      }
    }
  }
}

// GEMM2: per expert, h [n_e,1024] x down [1024, 128 cols] + LoRA, scaled by
// routing weight, atomicAdd into y. Block: 64 tokens x 128 cols, 4 waves.
__global__ __launch_bounds__(256) void k_gemm2(
    const unsigned short* __restrict__ hws, const float* __restrict__ down,
    const float* __restrict__ dlB, const float* __restrict__ ter2,
    const int* __restrict__ cnt, const int* __restrict__ list,
    const float* __restrict__ pw, float* __restrict__ y) {
  int ct = blockIdx.x, st = blockIdx.y, e = blockIdx.z;
  int n = cnt[e];
  if (st * 64 >= n) return;
  int tid = threadIdx.x;

  __shared__ int plist_s[64];
  __shared__ float ters[64][16];
  __shared__ float wts[64];
  __shared__ unsigned short Asub[64 * 64];
  __shared__ unsigned short Bsub[64 * 128];

  if (tid < 64) {
    int p = list[e * 512 + min(st * 64 + tid, n - 1)];
    plist_s[tid] = p;
    wts[tid] = pw[p];
  }
  __syncthreads();
  for (int i = tid; i < 64 * 16; i += 256)
    ters[i >> 4][i & 15] = ter2[plist_s[i >> 4] * 16 + (i & 15)];

  int lane = tid & 63, wv = tid >> 6;
  int lr = lane & 15, lh = lane >> 4;
  int wc = wv * 32;
  int c0 = ct * 128;

  f32x4 acc[4][2] = {};

  for (int kt = 0; kt < 16; ++kt) {
    int k0 = kt * 64;
    __syncthreads();
#pragma unroll
    for (int q = 0; q < 2; ++q) {
      int lin = tid + q * 256;
      int row = lin >> 3, k8 = (lin & 7) * 8;
      uint4 v = *(const uint4*)(hws + (size_t)plist_s[row] * 1024 + k0 + k8);
      *(uint4*)&Asub[row * 64 + (k8 ^ ((row & 7) << 3))] = v;
    }
#pragma unroll
    for (int q = 0; q < 8; ++q) {
      int lin = tid + q * 256;
      int k = lin >> 5, c4 = (lin & 31) * 4;
      float4 v = *(const float4*)(down + ((size_t)e * 1024 + k0 + k) * 2048 + c0 + c4);
      u16x4 b = { f2bf(v.x), f2bf(v.y), f2bf(v.z), f2bf(v.w) };
      *(u16x4*)&Bsub[k * 128 + (c4 ^ (((k >> 3) & 3) << 4))] = b;
    }
    __syncthreads();
#pragma unroll
    for (int ks = 0; ks < 64; ks += 32) {
      int kb = ks + lh * 8;
      int key = ((kb >> 3) & 3) << 4;
      s16x8 bfrag[2];
#pragma unroll
      for (int fc = 0; fc < 2; ++fc) {
        int colx = (wc + fc * 16 + lr) ^ key;
#pragma unroll
        for (int j = 0; j < 8; ++j)
          bfrag[fc][j] = (short)Bsub[(kb + j) * 128 + colx];
      }
#pragma unroll
      for (int fr = 0; fr < 4; ++fr) {
        int row = fr * 16 + lr;
        s16x8 a = *(const s16x8*)&Asub[row * 64 + (kb ^ ((row & 7) << 3))];
#pragma unroll
        for (int fc = 0; fc < 2; ++fc)
          acc[fr][fc] = __builtin_amdgcn_mfma_f32_16x16x32_bf16(a, bfrag[fc], acc[fr][fc], 0, 0, 0);
      }
    }
  }
#pragma unroll
  for (int fc = 0; fc < 2; ++fc) {
    int cl = wc + fc * 16 + lr;
    const float* d2p = dlB + ((size_t)e * 2048 + c0 + cl) * 16;
    float d2[16];
#pragma unroll
    for (int r = 0; r < 16; ++r) d2[r] = d2p[r];
#pragma unroll
    for (int fr = 0; fr < 4; ++fr) {
#pragma unroll
      for (int j = 0; j < 4; ++j) {
        int row = fr * 16 + lh * 4 + j;
        if (st * 64 + row < n) {
          float dd = 0.f;
#pragma unroll
          for (int r = 0; r < 16; ++r) dd += ters[row][r] * d2[r];
          float val = wts[row] * (acc[fr][fc][j] + 2.f * dd);
          int t = plist_s[row] >> 1;
          atomicAdd(&y[(size_t)t * 2048 + c0 + cl], val);
        }
      }
    }
  }
}

// ---------------------------------------------------------------------------
extern "C" void kernel_launch(void* const* d_in, const int* in_sizes, int n_in,
                              void* d_out, int out_size, void* d_ws, size_t ws_size,
                              hipStream_t stream) {
  (void)in_sizes; (void)n_in; (void)ws_size;
  const float* x    = (const float*)d_in[0];
  const float* gw   = (const float*)d_in[1];
  const float* gA   = (const float*)d_in[2];
  const float* gB   = (const float*)d_in[3];
  const float* gup  = (const float*)d_in[4];
  const float* down = (const float*)d_in[5];
  const float* gupA = (const float*)d_in[6];
  const float* gupB = (const float*)d_in[7];
  const float* dlA  = (const float*)d_in[8];
  const float* dlB  = (const float*)d_in[9];
  float* y = (float*)d_out;

  char* w = (char*)d_ws;
  float* Wg            = (float*)(w + OFF_WG);
  int*   cnt           = (int*)(w + OFF_CNT);
  int*   list          = (int*)(w + OFF_LIST);
  int*   pexp          = (int*)(w + OFF_PEXP);
  float* pw            = (float*)(w + OFF_PW);
  float* ter1          = (float*)(w + OFF_TER1);
  float* ter2          = (float*)(w + OFF_TER2);
  unsigned short* xbf  = (unsigned short*)(w + OFF_XBF);
  unsigned short* hws  = (unsigned short*)(w + OFF_H);

  hipMemsetAsync(cnt, 0, 8 * sizeof(int), stream);
  hipMemsetAsync(y, 0, (size_t)out_size * sizeof(float), stream);

  k_gatecomb<<<64, 256, 0, stream>>>(gw, gA, gB, Wg);
  k_xcvt<<<1024, 256, 0, stream>>>(x, xbf);
  k_router<<<512, 256, 0, stream>>>(x, Wg, cnt, list, pexp, pw);
  k_ter1<<<1024, 256, 0, stream>>>(x, gupA, pexp, ter1);
  k_gemm1<<<dim3(16, 8, 8), 256, 0, stream>>>(xbf, gup, gupB, ter1, cnt, list, hws);
  k_ter2<<<1024, 256, 0, stream>>>(hws, dlA, pexp, ter2);
  k_gemm2<<<dim3(16, 8, 8), 256, 0, stream>>>(hws, down, dlB, ter2, cnt, list, pw, y);
}

// Round 2
// 194.262 us; speedup vs baseline: 1.4220x; 1.4220x over previous
//
#include <hip/hip_runtime.h>

// ---------------------------------------------------------------------------
// MoE gated MLP with LoRA, top-2 of 8, T=512, H=2048, I=1024, R=16.
// Round 2: 8-wave blocks, split-K, single-barrier dbuf pipeline, transposed
// swizzled B in LDS, weight-read-once structure.
// ---------------------------------------------------------------------------

typedef short  s16x8 __attribute__((ext_vector_type(8)));
typedef float  f32x4 __attribute__((ext_vector_type(4)));
typedef unsigned short u16x4 __attribute__((ext_vector_type(4)));
typedef unsigned short u16x8 __attribute__((ext_vector_type(8)));

__device__ __forceinline__ unsigned short f2bf(float f) {
  unsigned u = __builtin_bit_cast(unsigned, f);
  u += 0x7fffu + ((u >> 16) & 1u);          // RNE
  return (unsigned short)(u >> 16);
}

// ---- workspace layout (bytes). [0, ZERO_SPAN) is memset to 0 each launch ----
#define OFF_CNT    0u          // 8 int, pad 256
#define OFF_TER1A  256u        // 512*128 f32  = 262144
#define OFF_TER2   262400u     // 1024*16 f32  = 65536
#define OFF_GUPWS  327936u     // 1024*2048 f32 = 8388608
#define ZERO_SPAN  8716544u
#define OFF_WG     8716544u    // 8*2048 f32   = 65536
#define OFF_LIST   8782080u    // 8*512 int    = 16384
#define OFF_PW     8798464u    // 1024 f32     = 4096
#define OFF_XBF    8802560u    // 512*2048 bf16 = 2097152
#define OFF_H      10899712u   // 1024*1024 bf16 = 2097152
// total ~13.0 MB

// ---------------------------------------------------------------------------
__global__ void k_gatecomb(const float* __restrict__ gw, const float* __restrict__ gA,
                           const float* __restrict__ gB, float* __restrict__ Wg) {
  int idx = blockIdx.x * 256 + threadIdx.x;   // 16384
  int e = idx >> 11, h = idx & 2047;
  float acc = gw[idx];
#pragma unroll
  for (int r = 0; r < 16; ++r)
    acc += 2.0f * gB[e * 16 + r] * gA[r * 2048 + h];
  Wg[idx] = acc;
}

__global__ void k_xcvt(const float* __restrict__ x, unsigned short* __restrict__ xbf) {
  int idx = blockIdx.x * 256 + threadIdx.x;   // 262144, 4 elems each
  float4 v = ((const float4*)x)[idx];
  u16x4 o = { f2bf(v.x), f2bf(v.y), f2bf(v.z), f2bf(v.w) };
  ((u16x4*)xbf)[idx] = o;
}

// fp32 router (exact logits -> identical top-k to reference). Validated round 1.
__global__ void k_router(const float* __restrict__ x, const float* __restrict__ Wg,
                         int* __restrict__ cnt, int* __restrict__ list,
                         float* __restrict__ pw) {
  int t = blockIdx.x, tid = threadIdx.x;
  __shared__ float xs[2048];
  __shared__ float logits[8];
  for (int i = tid; i < 2048; i += 256) xs[i] = x[(size_t)t * 2048 + i];
  __syncthreads();
  int e = tid >> 5, l = tid & 31;
  float s = 0.f;
  for (int h = l; h < 2048; h += 32) s += xs[h] * Wg[e * 2048 + h];
#pragma unroll
  for (int off = 16; off >= 1; off >>= 1) s += __shfl_down(s, off, 32);
  if (l == 0) logits[e] = s;
  __syncthreads();
  if (tid == 0) {
    float m = logits[0];
#pragma unroll
    for (int i = 1; i < 8; ++i) m = fmaxf(m, logits[i]);
    float ex[8];
#pragma unroll
    for (int i = 0; i < 8; ++i) ex[i] = __expf(logits[i] - m);
    int e1 = 0; float v1 = ex[0];
#pragma unroll
    for (int i = 1; i < 8; ++i) if (ex[i] > v1) { v1 = ex[i]; e1 = i; }
    int e2 = -1; float v2 = -1.f;
#pragma unroll
    for (int i = 0; i < 8; ++i) if (i != e1 && ex[i] > v2) { v2 = ex[i]; e2 = i; }
    float inv = 1.f / (v1 + v2);
    int p1 = 2 * t, p2 = 2 * t + 1;
    pw[p1] = v1 * inv;
    pw[p2] = v2 * inv;
    int s1 = atomicAdd(&cnt[e1], 1); list[e1 * 512 + s1] = p1;
    int s2 = atomicAdd(&cnt[e2], 1); list[e2 * 512 + s2] = p2;
  }
}

// ter1all[t][er] = x[t] . gupA_flat[er]  (er = e*16+r), MFMA GEMM 512x128xK2048.
__global__ __launch_bounds__(512) void k_ter1all(
    const unsigned short* __restrict__ xbf, const float* __restrict__ gupA,
    float* __restrict__ ter1all) {
  int trow = blockIdx.x, kcc = blockIdx.y;
  int tid = threadIdx.x;
  __shared__ unsigned short Ap[2][64 * 64];
  __shared__ unsigned short Bp[2][128 * 64];
  const int k0b = kcc * 512;

  int rowA = tid >> 3, k16A = tid & 7;
  const unsigned short* aSrc = xbf + (size_t)(trow * 64 + rowA) * 2048 + k0b + k16A * 8;
  int aOff = rowA * 64 + ((k16A * 8) ^ ((rowA & 7) << 3));

  const float* bSrc[2]; int bOff[2];
#pragma unroll
  for (int s = 0; s < 2; ++s) {
    int slot = tid + s * 512;
    int er = slot >> 3, kg = slot & 7;
    bSrc[s] = gupA + (size_t)er * 2048 + k0b + kg * 8;
    bOff[s] = er * 64 + ((kg * 8) ^ ((er & 7) << 3));
  }
  int lane = tid & 63, wv = tid >> 6;
  int lr = lane & 15, lh = lane >> 4;

  uint4 apre; float4 bpre[2][2];
#define TA_ISSUE(T) { int kk = (T) * 64;                                   \
    apre = *(const uint4*)(aSrc + kk);                                     \
    _Pragma("unroll") for (int s = 0; s < 2; ++s) {                        \
      bpre[s][0] = *(const float4*)(bSrc[s] + kk);                         \
      bpre[s][1] = *(const float4*)(bSrc[s] + kk + 4); } }

  f32x4 acc[4] = {};
  TA_ISSUE(0);
  for (int t = 0; t < 8; ++t) {
    int buf = t & 1;
    *(uint4*)&Ap[buf][aOff] = apre;
#pragma unroll
    for (int s = 0; s < 2; ++s) {
      u16x8 o;
      o[0]=f2bf(bpre[s][0].x); o[1]=f2bf(bpre[s][0].y); o[2]=f2bf(bpre[s][0].z); o[3]=f2bf(bpre[s][0].w);
      o[4]=f2bf(bpre[s][1].x); o[5]=f2bf(bpre[s][1].y); o[6]=f2bf(bpre[s][1].z); o[7]=f2bf(bpre[s][1].w);
      *(u16x8*)&Bp[buf][bOff[s]] = o;
    }
    __syncthreads();
    if (t < 7) TA_ISSUE(t + 1);
#pragma unroll
    for (int ks = 0; ks < 64; ks += 32) {
      int kb = ks + lh * 8;
      int bc = wv * 16 + lr;
      s16x8 b = *(const s16x8*)&Bp[buf][bc * 64 + (kb ^ ((bc & 7) << 3))];
#pragma unroll
      for (int fr = 0; fr < 4; ++fr) {
        int ar = fr * 16 + lr;
        s16x8 a = *(const s16x8*)&Ap[buf][ar * 64 + (kb ^ ((ar & 7) << 3))];
        acc[fr] = __builtin_amdgcn_mfma_f32_16x16x32_bf16(a, b, acc[fr], 0, 0, 0);
      }
    }
  }
#undef TA_ISSUE
#pragma unroll
  for (int fr = 0; fr < 4; ++fr)
#pragma unroll
    for (int j = 0; j < 4; ++j) {
      int tok = trow * 64 + fr * 16 + lh * 4 + j;
      atomicAdd(&ter1all[tok * 128 + wv * 16 + lr], acc[fr][j]);
    }
}

// GEMM1: gathered x rows [<=128] x gup[e] (flat 2048 cols), split-K=2,
// fp32 partials atomicAdd into gup_ws. 8 waves, dbuf, 1 barrier / K-step.
__global__ __launch_bounds__(512) void k_gemm1(
    const unsigned short* __restrict__ xbf, const float* __restrict__ gup,
    const int* __restrict__ cnt, const int* __restrict__ list,
    float* __restrict__ gup_ws) {
  int ct = blockIdx.x, st = blockIdx.y, ez = blockIdx.z;
  int e = ez >> 1, kc = ez & 1;
  int n = cnt[e];
  if (st * 128 >= n) return;
  int tid = threadIdx.x;

  __shared__ unsigned short Ap[2][128 * 64];   // [row][k] swizzled
  __shared__ unsigned short Bp[2][128 * 64];   // [col][k] transposed, swizzled

  const int c0 = ct * 128;
  const int k0b = kc * 1024;

  const unsigned short* aSrc[2]; int aOff[2];
#pragma unroll
  for (int s = 0; s < 2; ++s) {
    int slot = tid + s * 512;
    int row = slot >> 3, k16 = slot & 7;
    int p = list[e * 512 + min(st * 128 + row, n - 1)];
    aSrc[s] = xbf + (size_t)(p >> 1) * 2048 + k0b + k16 * 8;
    aOff[s] = row * 64 + ((k16 * 8) ^ ((row & 7) << 3));
  }
  const float* bSrc[2]; int bOff[2];
#pragma unroll
  for (int s = 0; s < 2; ++s) {
    int slot = tid + s * 512;
    int col = slot & 127, kg = slot >> 7;
    bSrc[s] = gup + ((size_t)e * 2048 + k0b + kg * 8) * 2048 + c0 + col;
    bOff[s] = col * 64 + ((kg * 8) ^ ((col & 7) << 3));
  }
  int lane = tid & 63, wv = tid >> 6;
  int lr = lane & 15, lh = lane >> 4;
  int wr = wv >> 2, wcI = wv & 3;

  uint4 apre[2]; float bpre[2][8];
#define G1_ISSUE(T) { int kk = (T) * 64;                                   \
    _Pragma("unroll") for (int s = 0; s < 2; ++s)                          \
        apre[s] = *(const uint4*)(aSrc[s] + kk);                           \
    _Pragma("unroll") for (int s = 0; s < 2; ++s)                          \
      _Pragma("unroll") for (int j = 0; j < 8; ++j)                        \
        bpre[s][j] = bSrc[s][(size_t)(kk + j) * 2048]; }

  f32x4 acc[4][2] = {};
  G1_ISSUE(0);
  for (int t = 0; t < 16; ++t) {
    int buf = t & 1;
#pragma unroll
    for (int s = 0; s < 2; ++s) *(uint4*)&Ap[buf][aOff[s]] = apre[s];
#pragma unroll
    for (int s = 0; s < 2; ++s) {
      u16x8 o;
#pragma unroll
      for (int j = 0; j < 8; ++j) o[j] = f2bf(bpre[s][j]);
      *(u16x8*)&Bp[buf][bOff[s]] = o;
    }
    __syncthreads();
    if (t < 15) G1_ISSUE(t + 1);
#pragma unroll
    for (int ks = 0; ks < 64; ks += 32) {
      int kb = ks + lh * 8;
      s16x8 a[4], b[2];
#pragma unroll
      for (int fr = 0; fr < 4; ++fr) {
        int ar = wr * 64 + fr * 16 + lr;
        a[fr] = *(const s16x8*)&Ap[buf][ar * 64 + (kb ^ ((ar & 7) << 3))];
      }
#pragma unroll
      for (int fc = 0; fc < 2; ++fc) {
        int bc = wcI * 32 + fc * 16 + lr;
        b[fc] = *(const s16x8*)&Bp[buf][bc * 64 + (kb ^ ((bc & 7) << 3))];
      }
#pragma unroll
      for (int fr = 0; fr < 4; ++fr)
#pragma unroll
        for (int fc = 0; fc < 2; ++fc)
          acc[fr][fc] = __builtin_amdgcn_mfma_f32_16x16x32_bf16(a[fr], b[fc], acc[fr][fc], 0, 0, 0);
    }
  }
#undef G1_ISSUE
#pragma unroll
  for (int fr = 0; fr < 4; ++fr) {
#pragma unroll
    for (int j = 0; j < 4; ++j) {
      int row = wr * 64 + fr * 16 + lh * 4 + j;
      if (st * 128 + row < n) {
        int p = list[e * 512 + st * 128 + row];
#pragma unroll
        for (int fc = 0; fc < 2; ++fc) {
          int col = c0 + wcI * 32 + fc * 16 + lr;
          atomicAdd(&gup_ws[(size_t)p * 2048 + col], acc[fr][fc][j]);
        }
      }
    }
  }
}

// h = silu(g + 2*dg) * (u + 2*du) from gup_ws + ter1all x gupB. 16 slots/block.
__global__ __launch_bounds__(256) void k_hsilu(
    const float* __restrict__ gup_ws, const float* __restrict__ gupB,
    const float* __restrict__ ter1all,
    const int* __restrict__ cnt, const int* __restrict__ list,
    unsigned short* __restrict__ h) {
  int slc = blockIdx.x, e = blockIdx.y;
  int n = cnt[e];
  if (slc * 16 >= n) return;
  int tid = threadIdx.x;
  __shared__ int pl[16];
  __shared__ float ters[16][16];
  if (tid < 16) pl[tid] = list[e * 512 + min(slc * 16 + tid, n - 1)];
  __syncthreads();
  {
    int s = tid >> 4, r = tid & 15;
    ters[s][r] = ter1all[(pl[s] >> 1) * 128 + e * 16 + r];
  }
  __syncthreads();
  int smax = min(16, n - slc * 16);
#pragma unroll
  for (int ic = 0; ic < 4; ++ic) {
    int i = ic * 256 + tid;
    const float* g2p = gupB + ((size_t)e * 2048 + i) * 16;
    const float* u2p = gupB + ((size_t)e * 2048 + 1024 + i) * 16;
    float g2[16], u2[16];
#pragma unroll
    for (int r = 0; r < 16; ++r) { g2[r] = g2p[r]; u2[r] = u2p[r]; }
    for (int s = 0; s < smax; ++s) {
      int p = pl[s];
      float g = gup_ws[(size_t)p * 2048 + i];
      float u = gup_ws[(size_t)p * 2048 + 1024 + i];
      float dg = 0.f, du = 0.f;
#pragma unroll
      for (int r = 0; r < 16; ++r) { float tv = ters[s][r]; dg += tv * g2[r]; du += tv * u2[r]; }
      float gv = g + 2.f * dg, uv = u + 2.f * du;
      h[(size_t)p * 1024 + i] = f2bf(gv / (1.f + __expf(-gv)) * uv);
    }
  }
}

// ter2[p][r] = h[p] . dlA[e][r], grouped MFMA GEMM (BN=16), split-K=4.
__global__ __launch_bounds__(512) void k_ter2(
    const unsigned short* __restrict__ h, const float* __restrict__ dlA,
    const int* __restrict__ cnt, const int* __restrict__ list,
    float* __restrict__ ter2) {
  int st = blockIdx.x, kcc = blockIdx.y, e = blockIdx.z;
  int n = cnt[e];
  if (st * 128 >= n) return;
  int tid = threadIdx.x;
  __shared__ unsigned short Ap[2][128 * 64];
  __shared__ unsigned short Bp[2][16 * 64];
  const int k0b = kcc * 256;

  const unsigned short* aSrc[2]; int aOff[2];
#pragma unroll
  for (int s = 0; s < 2; ++s) {
    int slot = tid + s * 512;
    int row = slot >> 3, k16 = slot & 7;
    int p = list[e * 512 + min(st * 128 + row, n - 1)];
    aSrc[s] = h + (size_t)p * 1024 + k0b + k16 * 8;
    aOff[s] = row * 64 + ((k16 * 8) ^ ((row & 7) << 3));
  }
  const float* bSrc = nullptr; int bOff = 0;
  if (tid < 128) {
    int r = tid >> 3, kg = tid & 7;
    bSrc = dlA + ((size_t)e * 16 + r) * 1024 + k0b + kg * 8;
    bOff = r * 64 + ((kg * 8) ^ ((r & 7) << 3));
  }
  int lane = tid & 63, wv = tid >> 6;
  int lr = lane & 15, lh = lane >> 4;

  uint4 apre[2]; float4 bpre[2];
#define T2_ISSUE(T) { int kk = (T) * 64;                                   \
    _Pragma("unroll") for (int s = 0; s < 2; ++s)                          \
        apre[s] = *(const uint4*)(aSrc[s] + kk);                           \
    if (tid < 128) { bpre[0] = *(const float4*)(bSrc + kk);                \
                     bpre[1] = *(const float4*)(bSrc + kk + 4); } }

  f32x4 acc = {};
  T2_ISSUE(0);
  for (int t = 0; t < 4; ++t) {
    int buf = t & 1;
#pragma unroll
    for (int s = 0; s < 2; ++s) *(uint4*)&Ap[buf][aOff[s]] = apre[s];
    if (tid < 128) {
      u16x8 o;
      o[0]=f2bf(bpre[0].x); o[1]=f2bf(bpre[0].y); o[2]=f2bf(bpre[0].z); o[3]=f2bf(bpre[0].w);
      o[4]=f2bf(bpre[1].x); o[5]=f2bf(bpre[1].y); o[6]=f2bf(bpre[1].z); o[7]=f2bf(bpre[1].w);
      *(u16x8*)&Bp[buf][bOff] = o;
    }
    __syncthreads();
    if (t < 3) T2_ISSUE(t + 1);
#pragma unroll
    for (int ks = 0; ks < 64; ks += 32) {
      int kb = ks + lh * 8;
      s16x8 b = *(const s16x8*)&Bp[buf][lr * 64 + (kb ^ ((lr & 7) << 3))];
      int ar = wv * 16 + lr;
      s16x8 a = *(const s16x8*)&Ap[buf][ar * 64 + (kb ^ ((ar & 7) << 3))];
      acc = __builtin_amdgcn_mfma_f32_16x16x32_bf16(a, b, acc, 0, 0, 0);
    }
  }
#undef T2_ISSUE
#pragma unroll
  for (int j = 0; j < 4; ++j) {
    int row = wv * 16 + lh * 4 + j;
    if (st * 128 + row < n) {
      int p = list[e * 512 + st * 128 + row];
      atomicAdd(&ter2[p * 16 + lr], acc[j]);
    }
  }
}

// GEMM2: gathered h rows x down[e], weighted atomicAdd into y. Split-K=2.
__global__ __launch_bounds__(512) void k_gemm2(
    const unsigned short* __restrict__ h, const float* __restrict__ down,
    const int* __restrict__ cnt, const int* __restrict__ list,
    const float* __restrict__ pw, float* __restrict__ y) {
  int ct = blockIdx.x, st = blockIdx.y, ez = blockIdx.z;
  int e = ez >> 1, kc = ez & 1;
  int n = cnt[e];
  if (st * 128 >= n) return;
  int tid = threadIdx.x;
  __shared__ unsigned short Ap[2][128 * 64];
  __shared__ unsigned short Bp[2][128 * 64];
  const int c0 = ct * 128;
  const int k0b = kc * 512;

  const unsigned short* aSrc[2]; int aOff[2];
#pragma unroll
  for (int s = 0; s < 2; ++s) {
    int slot = tid + s * 512;
    int row = slot >> 3, k16 = slot & 7;
    int p = list[e * 512 + min(st * 128 + row, n - 1)];
    aSrc[s] = h + (size_t)p * 1024 + k0b + k16 * 8;
    aOff[s] = row * 64 + ((k16 * 8) ^ ((row & 7) << 3));
  }
  const float* bSrc[2]; int bOff[2];
#pragma unroll
  for (int s = 0; s < 2; ++s) {
    int slot = tid + s * 512;
    int col = slot & 127, kg = slot >> 7;
    bSrc[s] = down + ((size_t)e * 1024 + k0b + kg * 8) * 2048 + c0 + col;
    bOff[s] = col * 64 + ((kg * 8) ^ ((col & 7) << 3));
  }
  int lane = tid & 63, wv = tid >> 6;
  int lr = lane & 15, lh = lane >> 4;
  int wr = wv >> 2, wcI = wv & 3;

  uint4 apre[2]; float bpre[2][8];
#define G2_ISSUE(T) { int kk = (T) * 64;                                   \
    _Pragma("unroll") for (int s = 0; s < 2; ++s)                          \
        apre[s] = *(const uint4*)(aSrc[s] + kk);                           \
    _Pragma("unroll") for (int s = 0; s < 2; ++s)                          \
      _Pragma("unroll") for (int j = 0; j < 8; ++j)                        \
        bpre[s][j] = bSrc[s][(size_t)(kk + j) * 2048]; }

  f32x4 acc[4][2] = {};
  G2_ISSUE(0);
  for (int t = 0; t < 8; ++t) {
    int buf = t & 1;
#pragma unroll
    for (int s = 0; s < 2; ++s) *(uint4*)&Ap[buf][aOff[s]] = apre[s];
#pragma unroll
    for (int s = 0; s < 2; ++s) {
      u16x8 o;
#pragma unroll
      for (int j = 0; j < 8; ++j) o[j] = f2bf(bpre[s][j]);
      *(u16x8*)&Bp[buf][bOff[s]] = o;
    }
    __syncthreads();
    if (t < 7) G2_ISSUE(t + 1);
#pragma unroll
    for (int ks = 0; ks < 64; ks += 32) {
      int kb = ks + lh * 8;
      s16x8 a[4], b[2];
#pragma unroll
      for (int fr = 0; fr < 4; ++fr) {
        int ar = wr * 64 + fr * 16 + lr;
        a[fr] = *(const s16x8*)&Ap[buf][ar * 64 + (kb ^ ((ar & 7) << 3))];
      }
#pragma unroll
      for (int fc = 0; fc < 2; ++fc) {
        int bc = wcI * 32 + fc * 16 + lr;
        b[fc] = *(const s16x8*)&Bp[buf][bc * 64 + (kb ^ ((bc & 7) << 3))];
      }
#pragma unroll
      for (int fr = 0; fr < 4; ++fr)
#pragma unroll
        for (int fc = 0; fc < 2; ++fc)
          acc[fr][fc] = __builtin_amdgcn_mfma_f32_16x16x32_bf16(a[fr], b[fc], acc[fr][fc], 0, 0, 0);
    }
  }
#undef G2_ISSUE
#pragma unroll
  for (int fr = 0; fr < 4; ++fr) {
#pragma unroll
    for (int j = 0; j < 4; ++j) {
      int row = wr * 64 + fr * 16 + lh * 4 + j;
      if (st * 128 + row < n) {
        int p = list[e * 512 + st * 128 + row];
        float wt = pw[p];
        size_t tbase = (size_t)(p >> 1) * 2048;
#pragma unroll
        for (int fc = 0; fc < 2; ++fc) {
          int col = c0 + wcI * 32 + fc * 16 + lr;
          atomicAdd(&y[tbase + col], wt * acc[fr][fc][j]);
        }
      }
    }
  }
}

// y += wt * 2 * (ter2 x dlB^T): rank-16 down-LoRA term, 16 slots/block.
__global__ __launch_bounds__(256) void k_dlora(
    const float* __restrict__ ter2, const float* __restrict__ dlB,
    const int* __restrict__ cnt, const int* __restrict__ list,
    const float* __restrict__ pw, float* __restrict__ y) {
  int slc = blockIdx.x, e = blockIdx.y;
  int n = cnt[e];
  if (slc * 16 >= n) return;
  int tid = threadIdx.x;
  __shared__ int tok[16];
  __shared__ float wts[16];
  __shared__ float t2s[16][16];
  if (tid < 16) {
    int p = list[e * 512 + min(slc * 16 + tid, n - 1)];
    tok[tid] = p >> 1;
    wts[tid] = pw[p];
  }
  __syncthreads();
  {
    int s = tid >> 4, r = tid & 15;
    int p = list[e * 512 + min(slc * 16 + s, n - 1)];
    t2s[s][r] = ter2[p * 16 + r];
  }
  __syncthreads();
  int smax = min(16, n - slc * 16);
#pragma unroll
  for (int ic = 0; ic < 8; ++ic) {
    int col = ic * 256 + tid;
    const float* d2p = dlB + ((size_t)e * 2048 + col) * 16;
    float d2[16];
#pragma unroll
    for (int r = 0; r < 16; ++r) d2[r] = d2p[r];
    for (int s = 0; s < smax; ++s) {
      float dd = 0.f;
#pragma unroll
      for (int r = 0; r < 16; ++r) dd += t2s[s][r] * d2[r];
      atomicAdd(&y[(size_t)tok[s] * 2048 + col], 2.f * wts[s] * dd);
    }
  }
}

// ---------------------------------------------------------------------------
extern "C" void kernel_launch(void* const* d_in, const int* in_sizes, int n_in,
                              void* d_out, int out_size, void* d_ws, size_t ws_size,
                              hipStream_t stream) {
  (void)in_sizes; (void)n_in; (void)ws_size;
  const float* x    = (const float*)d_in[0];
  const float* gw   = (const float*)d_in[1];
  const float* gA   = (const float*)d_in[2];
  const float* gB   = (const float*)d_in[3];
  const float* gup  = (const float*)d_in[4];
  const float* down = (const float*)d_in[5];
  const float* gupA = (const float*)d_in[6];
  const float* gupB = (const float*)d_in[7];
  const float* dlA  = (const float*)d_in[8];
  const float* dlB  = (const float*)d_in[9];
  float* y = (float*)d_out;

  char* w = (char*)d_ws;
  int*   cnt           = (int*)(w + OFF_CNT);
  float* ter1all       = (float*)(w + OFF_TER1A);
  float* ter2          = (float*)(w + OFF_TER2);
  float* gup_ws        = (float*)(w + OFF_GUPWS);
  float* Wg            = (float*)(w + OFF_WG);
  int*   list          = (int*)(w + OFF_LIST);
  float* pw            = (float*)(w + OFF_PW);
  unsigned short* xbf  = (unsigned short*)(w + OFF_XBF);
  unsigned short* hbuf = (unsigned short*)(w + OFF_H);

  hipMemsetAsync(w, 0, ZERO_SPAN, stream);
  hipMemsetAsync(y, 0, (size_t)out_size * sizeof(float), stream);

  k_gatecomb<<<64, 256, 0, stream>>>(gw, gA, gB, Wg);
  k_xcvt<<<1024, 256, 0, stream>>>(x, xbf);
  k_router<<<512, 256, 0, stream>>>(x, Wg, cnt, list, pw);
  k_ter1all<<<dim3(8, 4), 512, 0, stream>>>(xbf, gupA, ter1all);
  k_gemm1<<<dim3(16, 4, 16), 512, 0, stream>>>(xbf, gup, cnt, list, gup_ws);
  k_hsilu<<<dim3(32, 8), 256, 0, stream>>>(gup_ws, gupB, ter1all, cnt, list, hbuf);
  k_ter2<<<dim3(4, 4, 8), 512, 0, stream>>>(hbuf, dlA, cnt, list, ter2);
  k_gemm2<<<dim3(16, 4, 16), 512, 0, stream>>>(hbuf, down, cnt, list, pw, y);
  k_dlora<<<dim3(32, 8), 256, 0, stream>>>(ter2, dlB, cnt, list, pw, y);
}

// Round 4
// 188.751 us; speedup vs baseline: 1.4635x; 1.0292x over previous
//
#include <hip/hip_runtime.h>

// ---------------------------------------------------------------------------
// MoE gated MLP with LoRA, top-2 of 8, T=512, H=2048, I=1024, R=16.
// Round 4: round-3 structure with the k_dlora grid fix (y-dim 4 -> 8; cols
// 1024..2047 of the down-LoRA term were never added).
// ---------------------------------------------------------------------------

typedef short  s16x8 __attribute__((ext_vector_type(8)));
typedef float  f32x4 __attribute__((ext_vector_type(4)));
typedef unsigned short u16x8 __attribute__((ext_vector_type(8)));

__device__ __forceinline__ unsigned short f2bf(float f) {
  unsigned u = __builtin_bit_cast(unsigned, f);
  u += 0x7fffu + ((u >> 16) & 1u);          // RNE
  return (unsigned short)(u >> 16);
}

#define GWW 2064   // gup_ws row width: 2048 gup cols + 16 LoRA-ter1 cols

// ---- workspace layout (bytes). [0, ZERO_SPAN) memset to 0 each launch ----
#define OFF_CNT    0u          // 8 int (pad 256)
#define OFF_TER2   256u        // 1024*16 f32 = 65536
#define OFF_GWS    65792u      // 1024*2064 f32 = 8454144
#define ZERO_SPAN  8519936u
#define OFF_LIST   8519936u    // 8*512 int = 16384
#define OFF_PW     8536320u    // 1024 f32 = 4096
#define OFF_WG     8540416u    // 8*2048 f32 = 65536
#define OFF_XBF    8605952u    // 512*2048 bf16 = 2097152
#define OFF_H      10703104u   // 1024*1024 bf16 = 2097152
// total 12800256 (~12.8 MB)

// ---------------------------------------------------------------------------
__global__ void k_gatecomb(const float* __restrict__ gw, const float* __restrict__ gA,
                           const float* __restrict__ gB, float* __restrict__ Wg) {
  int idx = blockIdx.x * 256 + threadIdx.x;   // 16384
  int e = idx >> 11, h = idx & 2047;
  float acc = gw[idx];
#pragma unroll
  for (int r = 0; r < 16; ++r)
    acc += 2.0f * gB[e * 16 + r] * gA[r * 2048 + h];
  Wg[idx] = acc;
}

// fp32 router (exact logits -> identical top-k to reference) + fused x->bf16.
__global__ void k_router(const float* __restrict__ x, const float* __restrict__ Wg,
                         int* __restrict__ cnt, int* __restrict__ list,
                         float* __restrict__ pw, unsigned short* __restrict__ xbf) {
  int t = blockIdx.x, tid = threadIdx.x;
  __shared__ float xs[2048];
  __shared__ float logits[8];
  for (int i = tid; i < 2048; i += 256) xs[i] = x[(size_t)t * 2048 + i];
  __syncthreads();
  {  // fused bf16 conversion of this token's row
    u16x8 o;
#pragma unroll
    for (int j = 0; j < 8; ++j) o[j] = f2bf(xs[tid * 8 + j]);
    *(u16x8*)(xbf + (size_t)t * 2048 + tid * 8) = o;
  }
  int e = tid >> 5, l = tid & 31;
  float s = 0.f;
  for (int h = l; h < 2048; h += 32) s += xs[h] * Wg[e * 2048 + h];
#pragma unroll
  for (int off = 16; off >= 1; off >>= 1) s += __shfl_down(s, off, 32);
  if (l == 0) logits[e] = s;
  __syncthreads();
  if (tid == 0) {
    float m = logits[0];
#pragma unroll
    for (int i = 1; i < 8; ++i) m = fmaxf(m, logits[i]);
    float ex[8];
#pragma unroll
    for (int i = 0; i < 8; ++i) ex[i] = __expf(logits[i] - m);
    int e1 = 0; float v1 = ex[0];
#pragma unroll
    for (int i = 1; i < 8; ++i) if (ex[i] > v1) { v1 = ex[i]; e1 = i; }
    int e2 = -1; float v2 = -1.f;
#pragma unroll
    for (int i = 0; i < 8; ++i) if (i != e1 && ex[i] > v2) { v2 = ex[i]; e2 = i; }
    float inv = 1.f / (v1 + v2);
    int p1 = 2 * t, p2 = 2 * t + 1;
    pw[p1] = v1 * inv;
    pw[p2] = v2 * inv;
    int s1 = atomicAdd(&cnt[e1], 1); list[e1 * 512 + s1] = p1;
    int s2 = atomicAdd(&cnt[e2], 1); list[e2 * 512 + s2] = p2;
  }
}

// ---------------------------------------------------------------------------
// GEMM1: gathered x rows [BM=128] x gup[e] [BN=64 cols], split-K=2 (K=1024
// each, NT=16 steps of 64). ct==32 is the LoRA-A tile (16 cols of gupA).
// 2-deep register pipeline.
__global__ __launch_bounds__(512) void k_gemm1(
    const unsigned short* __restrict__ xbf, const float* __restrict__ gup,
    const float* __restrict__ gupA,
    const int* __restrict__ cnt, const int* __restrict__ list,
    float* __restrict__ gws) {
  const int ct = blockIdx.x;                 // 0..32
  const int st = blockIdx.y >> 1, kc = blockIdx.y & 1;
  const int e  = blockIdx.z;
  const int n = cnt[e];
  if (n == 0 || st * 128 >= n) return;
  const int tid = threadIdx.x;

  __shared__ unsigned short Ap[2][128 * 64];   // [row][k] swizzled
  __shared__ unsigned short Bp[2][64 * 64];    // [col][k] swizzled

  const int k0b = kc * 1024;
  const bool lora = (ct == 32);
  const int c0 = ct * 64;

  const unsigned short *aSrc0, *aSrc1;
  int aOff0, aOff1;
  {
    int row = tid >> 3, k16 = tid & 7;
    int p = list[e * 512 + min(st * 128 + row, n - 1)];
    aSrc0 = xbf + (size_t)(p >> 1) * 2048 + k0b + k16 * 8;
    aOff0 = row * 64 + ((k16 * 8) ^ ((row & 7) << 3));
    int slot = tid + 512;
    row = slot >> 3; k16 = slot & 7;
    p = list[e * 512 + min(st * 128 + row, n - 1)];
    aSrc1 = xbf + (size_t)(p >> 1) * 2048 + k0b + k16 * 8;
    aOff1 = row * 64 + ((k16 * 8) ^ ((row & 7) << 3));
  }
  const int bcol = tid & 63, kgrp = tid >> 6;
  size_t brstr;
  const float* bSrc;
  if (!lora) {
    brstr = 2048;
    bSrc = gup + ((size_t)e * 2048 + k0b + kgrp * 8) * 2048 + c0 + bcol;
  } else {
    brstr = 1;
    bSrc = gupA + ((size_t)e * 16 + (bcol & 15)) * 2048 + k0b + kgrp * 8;
  }
  const int bOff = bcol * 64 + ((kgrp * 8) ^ ((bcol & 7) << 3));

  const int lane = tid & 63, wv = tid >> 6;
  const int lr = lane & 15, lh = lane >> 4;
  const int wr = wv >> 1, wc = wv & 1;       // 4x2 waves, 32x32 each

  uint4 a0A, a1A, a0B, a1B;
  float bA[8], bB[8];

#define G1_LOAD(SUF, T) {                                        \
    const int kk = (T) * 64;                                     \
    a0##SUF = *(const uint4*)(aSrc0 + kk);                       \
    a1##SUF = *(const uint4*)(aSrc1 + kk);                       \
    _Pragma("unroll") for (int j = 0; j < 8; ++j)                \
      b##SUF[j] = bSrc[(size_t)(kk + j) * brstr]; }

#define G1_BODY(BUF, SUF, NXT) {                                               \
    *(uint4*)&Ap[BUF][aOff0] = a0##SUF;                                        \
    *(uint4*)&Ap[BUF][aOff1] = a1##SUF;                                        \
    { u16x8 o;                                                                 \
      _Pragma("unroll") for (int j = 0; j < 8; ++j) o[j] = f2bf(b##SUF[j]);    \
      *(u16x8*)&Bp[BUF][bOff] = o; }                                           \
    __syncthreads();                                                           \
    if ((NXT) < 16) G1_LOAD(SUF, NXT);                                         \
    _Pragma("unroll") for (int ks = 0; ks < 64; ks += 32) {                    \
      int kb = ks + lh * 8;                                                    \
      s16x8 af[2], bf_[2];                                                     \
      _Pragma("unroll") for (int q = 0; q < 2; ++q) {                          \
        int ar = wr * 32 + q * 16 + lr;                                        \
        af[q] = *(const s16x8*)&Ap[BUF][ar * 64 + (kb ^ ((ar & 7) << 3))];     \
        int bc = wc * 32 + q * 16 + lr;                                        \
        bf_[q] = *(const s16x8*)&Bp[BUF][bc * 64 + (kb ^ ((bc & 7) << 3))];    \
      }                                                                        \
      _Pragma("unroll") for (int q = 0; q < 2; ++q)                            \
        _Pragma("unroll") for (int r = 0; r < 2; ++r)                          \
          acc[q][r] = __builtin_amdgcn_mfma_f32_16x16x32_bf16(af[q], bf_[r], acc[q][r], 0, 0, 0); \
    } }

  f32x4 acc[2][2] = {};
  G1_LOAD(A, 0);
  G1_LOAD(B, 1);
  for (int tt = 0; tt < 16; tt += 2) {
    G1_BODY(0, A, tt + 2);
    G1_BODY(1, B, tt + 3);
  }
#undef G1_LOAD
#undef G1_BODY

#pragma unroll
  for (int q = 0; q < 2; ++q) {
#pragma unroll
    for (int j = 0; j < 4; ++j) {
      int row = wr * 32 + q * 16 + lh * 4 + j;
      if (st * 128 + row < n) {
        int p = list[e * 512 + st * 128 + row];
        float* grow = gws + (size_t)p * GWW;
#pragma unroll
        for (int r = 0; r < 2; ++r) {
          int col = wc * 32 + r * 16 + lr;
          if (!lora) atomicAdd(grow + c0 + col, acc[q][r][j]);
          else if (col < 16) atomicAdd(grow + 2048 + col, acc[q][r][j]);
        }
      }
    }
  }
}

// h = silu(g + 2*dg) * (u + 2*du); dg/du from LoRA ters stored in gws[2048+].
__global__ __launch_bounds__(256) void k_hsilu(
    const float* __restrict__ gws, const float* __restrict__ gupB,
    const int* __restrict__ cnt, const int* __restrict__ list,
    unsigned short* __restrict__ h) {
  int slc = blockIdx.x, ic = blockIdx.y, e = blockIdx.z;
  int n = cnt[e];
  if (slc * 16 >= n) return;
  int tid = threadIdx.x;
  __shared__ int pl[16];
  __shared__ float ters[16][16];
  if (tid < 16) pl[tid] = list[e * 512 + min(slc * 16 + tid, n - 1)];
  __syncthreads();
  {
    int s = tid >> 4, r = tid & 15;
    ters[s][r] = gws[(size_t)pl[s] * GWW + 2048 + r];
  }
  __syncthreads();
  int smax = min(16, n - slc * 16);
  int i = ic * 256 + tid;
  const float4* g4 = (const float4*)(gupB + ((size_t)e * 2048 + i) * 16);
  const float4* u4 = (const float4*)(gupB + ((size_t)e * 2048 + 1024 + i) * 16);
  float g2[16], u2[16];
#pragma unroll
  for (int q = 0; q < 4; ++q) {
    float4 gv = g4[q], uv = u4[q];
    g2[q*4+0]=gv.x; g2[q*4+1]=gv.y; g2[q*4+2]=gv.z; g2[q*4+3]=gv.w;
    u2[q*4+0]=uv.x; u2[q*4+1]=uv.y; u2[q*4+2]=uv.z; u2[q*4+3]=uv.w;
  }
#pragma unroll
  for (int s = 0; s < 16; ++s) {
    int p = pl[s];
    float g = gws[(size_t)p * GWW + i];
    float u = gws[(size_t)p * GWW + 1024 + i];
    float dg = 0.f, du = 0.f;
#pragma unroll
    for (int r = 0; r < 16; ++r) { float tv = ters[s][r]; dg += tv * g2[r]; du += tv * u2[r]; }
    float gv = g + 2.f * dg, uv = u + 2.f * du;
    if (s < smax) h[(size_t)p * 1024 + i] = f2bf(gv / (1.f + __expf(-gv)) * uv);
  }
}

// GEMM2: gathered h rows x down[e], weighted atomicAdd into y. ct==32 is the
// dlA LoRA tile -> ter2. Same 2-deep pipeline; K=512 per kc, NT=8.
__global__ __launch_bounds__(512) void k_gemm2(
    const unsigned short* __restrict__ h, const float* __restrict__ down,
    const float* __restrict__ dlA,
    const int* __restrict__ cnt, const int* __restrict__ list,
    const float* __restrict__ pw, float* __restrict__ ter2,
    float* __restrict__ y) {
  const int ct = blockIdx.x;                 // 0..32
  const int st = blockIdx.y >> 1, kc = blockIdx.y & 1;
  const int e  = blockIdx.z;
  const int n = cnt[e];
  if (n == 0 || st * 128 >= n) return;
  const int tid = threadIdx.x;

  __shared__ unsigned short Ap[2][128 * 64];
  __shared__ unsigned short Bp[2][64 * 64];

  const int k0b = kc * 512;
  const bool lora = (ct == 32);
  const int c0 = ct * 64;

  const unsigned short *aSrc0, *aSrc1;
  int aOff0, aOff1;
  {
    int row = tid >> 3, k16 = tid & 7;
    int p = list[e * 512 + min(st * 128 + row, n - 1)];
    aSrc0 = h + (size_t)p * 1024 + k0b + k16 * 8;
    aOff0 = row * 64 + ((k16 * 8) ^ ((row & 7) << 3));
    int slot = tid + 512;
    row = slot >> 3; k16 = slot & 7;
    p = list[e * 512 + min(st * 128 + row, n - 1)];
    aSrc1 = h + (size_t)p * 1024 + k0b + k16 * 8;
    aOff1 = row * 64 + ((k16 * 8) ^ ((row & 7) << 3));
  }
  const int bcol = tid & 63, kgrp = tid >> 6;
  size_t brstr;
  const float* bSrc;
  if (!lora) {
    brstr = 2048;
    bSrc = down + ((size_t)e * 1024 + k0b + kgrp * 8) * 2048 + c0 + bcol;
  } else {
    brstr = 1;
    bSrc = dlA + ((size_t)e * 16 + (bcol & 15)) * 1024 + k0b + kgrp * 8;
  }
  const int bOff = bcol * 64 + ((kgrp * 8) ^ ((bcol & 7) << 3));

  const int lane = tid & 63, wv = tid >> 6;
  const int lr = lane & 15, lh = lane >> 4;
  const int wr = wv >> 1, wc = wv & 1;

  uint4 a0A, a1A, a0B, a1B;
  float bA[8], bB[8];

#define G2_LOAD(SUF, T) {                                        \
    const int kk = (T) * 64;                                     \
    a0##SUF = *(const uint4*)(aSrc0 + kk);                       \
    a1##SUF = *(const uint4*)(aSrc1 + kk);                       \
    _Pragma("unroll") for (int j = 0; j < 8; ++j)                \
      b##SUF[j] = bSrc[(size_t)(kk + j) * brstr]; }

#define G2_BODY(BUF, SUF, NXT) {                                               \
    *(uint4*)&Ap[BUF][aOff0] = a0##SUF;                                        \
    *(uint4*)&Ap[BUF][aOff1] = a1##SUF;                                        \
    { u16x8 o;                                                                 \
      _Pragma("unroll") for (int j = 0; j < 8; ++j) o[j] = f2bf(b##SUF[j]);    \
      *(u16x8*)&Bp[BUF][bOff] = o; }                                           \
    __syncthreads();                                                           \
    if ((NXT) < 8) G2_LOAD(SUF, NXT);                                          \
    _Pragma("unroll") for (int ks = 0; ks < 64; ks += 32) {                    \
      int kb = ks + lh * 8;                                                    \
      s16x8 af[2], bf_[2];                                                     \
      _Pragma("unroll") for (int q = 0; q < 2; ++q) {                          \
        int ar = wr * 32 + q * 16 + lr;                                        \
        af[q] = *(const s16x8*)&Ap[BUF][ar * 64 + (kb ^ ((ar & 7) << 3))];     \
        int bc = wc * 32 + q * 16 + lr;                                        \
        bf_[q] = *(const s16x8*)&Bp[BUF][bc * 64 + (kb ^ ((bc & 7) << 3))];    \
      }                                                                        \
      _Pragma("unroll") for (int q = 0; q < 2; ++q)                            \
        _Pragma("unroll") for (int r = 0; r < 2; ++r)                          \
          acc[q][r] = __builtin_amdgcn_mfma_f32_16x16x32_bf16(af[q], bf_[r], acc[q][r], 0, 0, 0); \
    } }

  f32x4 acc[2][2] = {};
  G2_LOAD(A, 0);
  G2_LOAD(B, 1);
  for (int tt = 0; tt < 8; tt += 2) {
    G2_BODY(0, A, tt + 2);
    G2_BODY(1, B, tt + 3);
  }
#undef G2_LOAD
#undef G2_BODY

#pragma unroll
  for (int q = 0; q < 2; ++q) {
#pragma unroll
    for (int j = 0; j < 4; ++j) {
      int row = wr * 32 + q * 16 + lh * 4 + j;
      if (st * 128 + row < n) {
        int p = list[e * 512 + st * 128 + row];
#pragma unroll
        for (int r = 0; r < 2; ++r) {
          int col = wc * 32 + r * 16 + lr;
          if (!lora) {
            atomicAdd(&y[(size_t)(p >> 1) * 2048 + c0 + col], pw[p] * acc[q][r][j]);
          } else if (col < 16) {
            atomicAdd(&ter2[p * 16 + col], acc[q][r][j]);
          }
        }
      }
    }
  }
}

// y += 2 * wt * (ter2 . dlB[e][col][:]) — ic covers 2048 cols in 8 slices.
__global__ __launch_bounds__(256) void k_dlora(
    const float* __restrict__ ter2, const float* __restrict__ dlB,
    const int* __restrict__ cnt, const int* __restrict__ list,
    const float* __restrict__ pw, float* __restrict__ y) {
  int slc = blockIdx.x, ic = blockIdx.y, e = blockIdx.z;
  int n = cnt[e];
  if (slc * 16 >= n) return;
  int tid = threadIdx.x;
  __shared__ int pl[16];
  __shared__ float wts[16];
  __shared__ float t2s[16][16];
  if (tid < 16) {
    int p = list[e * 512 + min(slc * 16 + tid, n - 1)];
    pl[tid] = p;
    wts[tid] = pw[p];
  }
  __syncthreads();
  {
    int s = tid >> 4, r = tid & 15;
    t2s[s][r] = ter2[pl[s] * 16 + r];
  }
  __syncthreads();
  int smax = min(16, n - slc * 16);
  int col = ic * 256 + tid;
  const float4* d4 = (const float4*)(dlB + ((size_t)e * 2048 + col) * 16);
  float d2[16];
#pragma unroll
  for (int q = 0; q < 4; ++q) {
    float4 v = d4[q];
    d2[q*4+0]=v.x; d2[q*4+1]=v.y; d2[q*4+2]=v.z; d2[q*4+3]=v.w;
  }
#pragma unroll
  for (int s = 0; s < 16; ++s) {
    float dd = 0.f;
#pragma unroll
    for (int r = 0; r < 16; ++r) dd += t2s[s][r] * d2[r];
    if (s < smax)
      atomicAdd(&y[(size_t)(pl[s] >> 1) * 2048 + col], 2.f * wts[s] * dd);
  }
}

// ---------------------------------------------------------------------------
extern "C" void kernel_launch(void* const* d_in, const int* in_sizes, int n_in,
                              void* d_out, int out_size, void* d_ws, size_t ws_size,
                              hipStream_t stream) {
  (void)in_sizes; (void)n_in; (void)ws_size;
  const float* x    = (const float*)d_in[0];
  const float* gw   = (const float*)d_in[1];
  const float* gA   = (const float*)d_in[2];
  const float* gB   = (const float*)d_in[3];
  const float* gup  = (const float*)d_in[4];
  const float* down = (const float*)d_in[5];
  const float* gupA = (const float*)d_in[6];
  const float* gupB = (const float*)d_in[7];
  const float* dlA  = (const float*)d_in[8];
  const float* dlB  = (const float*)d_in[9];
  float* y = (float*)d_out;

  char* w = (char*)d_ws;
  int*   cnt           = (int*)(w + OFF_CNT);
  float* ter2          = (float*)(w + OFF_TER2);
  float* gws           = (float*)(w + OFF_GWS);
  int*   list          = (int*)(w + OFF_LIST);
  float* pw            = (float*)(w + OFF_PW);
  float* Wg            = (float*)(w + OFF_WG);
  unsigned short* xbf  = (unsigned short*)(w + OFF_XBF);
  unsigned short* hbuf = (unsigned short*)(w + OFF_H);

  hipMemsetAsync(w, 0, ZERO_SPAN, stream);
  hipMemsetAsync(y, 0, (size_t)out_size * sizeof(float), stream);

  k_gatecomb<<<64, 256, 0, stream>>>(gw, gA, gB, Wg);
  k_router<<<512, 256, 0, stream>>>(x, Wg, cnt, list, pw, xbf);
  k_gemm1<<<dim3(33, 8, 8), 512, 0, stream>>>(xbf, gup, gupA, cnt, list, gws);
  k_hsilu<<<dim3(32, 4, 8), 256, 0, stream>>>(gws, gupB, cnt, list, hbuf);
  k_gemm2<<<dim3(33, 8, 8), 512, 0, stream>>>(hbuf, down, dlA, cnt, list, pw, ter2, y);
  k_dlora<<<dim3(32, 8, 8), 256, 0, stream>>>(ter2, dlB, cnt, list, pw, y);
}